// Round 4
// baseline (109.882 us; speedup 1.0000x reference)
//
#include <hip/hip_runtime.h>
#include <math.h>

#define D_MODEL 128
#define D_STATE 64
#define VOCAB 2000
#define SEQ_L 4096
#define BATCH 32
#define JSPLIT 64
#define CHUNK (SEQ_L / JSPLIT)   // 64
#define SEG 32                   // j's per weights BLOCK (16 per half)
#define SEGH 16
#define LN_BLOCKS (VOCAB / 4)    // 500
#define W_BLOCKS (SEQ_L / SEG)   // 128
#define LN_EPS 1e-5f

// ============ Kernel A: LN-embed + pooled-conv weights (fused, independent) ==
// blocks [0, 500): layernorm 4 vocab rows each -> e_ln
// blocks [500, 628): Wv[j,m] = D_m + sum_n r_mn * (1 - q_mn^{L-j}),
//   q = exp(dt_m * A_n), r = C_mn / (1 - q), via geometric recurrence per SEGH j's.
__global__ __launch_bounds__(256) void fused_prep_kernel(
    const float* __restrict__ emb, const float* __restrict__ ln_w,
    const float* __restrict__ ln_b, const float* __restrict__ A_log,
    const float* __restrict__ Dp, const float* __restrict__ C_re,
    const float* __restrict__ log_dt, float* __restrict__ e_ln,
    float* __restrict__ Wv, int* __restrict__ cnt) {
  if (blockIdx.x < LN_BLOCKS) {
    if (blockIdx.x == 0 && threadIdx.x < BATCH) cnt[threadIdx.x] = 0;
    int v = blockIdx.x * 4 + (threadIdx.x >> 6);
    int t = threadIdx.x & 63;
    const float* row = emb + v * D_MODEL;
    float h0 = row[t];
    float h1 = row[t + 64];
    float s = h0 + h1;
#pragma unroll
    for (int off = 32; off; off >>= 1) s += __shfl_xor(s, off);
    float mu = s * (1.0f / D_MODEL);
    float d0 = h0 - mu, d1 = h1 - mu;
    float q = d0 * d0 + d1 * d1;
#pragma unroll
    for (int off = 32; off; off >>= 1) q += __shfl_xor(q, off);
    float var = q * (1.0f / D_MODEL);
    float rs = rsqrtf(var + LN_EPS);
    e_ln[v * D_MODEL + t]      = d0 * rs * ln_w[t]      + ln_b[t];
    e_ln[v * D_MODEL + t + 64] = d1 * rs * ln_w[t + 64] + ln_b[t + 64];
  } else {
    __shared__ float Ash[D_STATE];
    if (threadIdx.x < D_STATE) Ash[threadIdx.x] = -expf(A_log[threadIdx.x]);
    __syncthreads();
    int wb = blockIdx.x - LN_BLOCKS;
    int m = threadIdx.x & (D_MODEL - 1);
    int sub = threadIdx.x >> 7;               // 0 or 1
    int j0 = wb * SEG + sub * SEGH;
    float acc[SEGH];
#pragma unroll
    for (int k = 0; k < SEGH; ++k) acc[k] = 0.0f;
    float dt = expf(log_dt[m]);
    float bs = 0.0f;
    float r1_end = (float)(SEQ_L - j0 - (SEGH - 1));
    for (int n = 0; n < D_STATE; ++n) {
      float x = dt * Ash[n];                  // negative
      float q = expf(x);
      float r = C_re[m * D_STATE + n] / (1.0f - q);
      bs += r;
      float g = expf(x * r1_end);             // q^{L - j0 - 15}
      acc[SEGH - 1] += r * g;
#pragma unroll
      for (int jj = SEGH - 2; jj >= 0; --jj) {
        g *= q;
        acc[jj] += r * g;
      }
    }
    float base = Dp[m] + bs;
#pragma unroll
    for (int k = 0; k < SEGH; ++k)
      Wv[(j0 + k) * D_MODEL + m] = base - acc[k];
  }
}

// ============ Kernel B: gather-reduce + last-block finish =====================
// part[b,s,m] = sum_{j in chunk s} e_ln[x[b,j], m] * Wv[j, m]
// Last block per b pools the 64 partials, applies classifier, writes out[b].
__global__ __launch_bounds__(128) void reduce_final_kernel(
    const int* __restrict__ x, const float* __restrict__ e_ln,
    const float* __restrict__ Wv, const float* __restrict__ W_cls,
    const float* __restrict__ b_cls, float* __restrict__ part,
    int* __restrict__ cnt, float* __restrict__ out) {
  __shared__ int toks[CHUNK];
  __shared__ float red0[D_MODEL], red1[D_MODEL];
  __shared__ int lastFlag;
  int b = blockIdx.x;
  int sIdx = blockIdx.y;
  int m = threadIdx.x;
  if (m < CHUNK) toks[m] = x[b * SEQ_L + sIdx * CHUNK + m];
  __syncthreads();
  const float* wbase = Wv + sIdx * CHUNK * D_MODEL + m;
  float a0 = 0.0f, a1 = 0.0f, a2 = 0.0f, a3 = 0.0f;
#pragma unroll
  for (int j = 0; j < CHUNK; j += 4) {
    int t0 = toks[j], t1 = toks[j + 1], t2 = toks[j + 2], t3 = toks[j + 3];
    float e0 = e_ln[t0 * D_MODEL + m];
    float e1 = e_ln[t1 * D_MODEL + m];
    float e2 = e_ln[t2 * D_MODEL + m];
    float e3 = e_ln[t3 * D_MODEL + m];
    float w0 = wbase[(j + 0) * D_MODEL];
    float w1 = wbase[(j + 1) * D_MODEL];
    float w2 = wbase[(j + 2) * D_MODEL];
    float w3 = wbase[(j + 3) * D_MODEL];
    a0 = fmaf(e0, w0, a0);
    a1 = fmaf(e1, w1, a1);
    a2 = fmaf(e2, w2, a2);
    a3 = fmaf(e3, w3, a3);
  }
  part[(b * JSPLIT + sIdx) * D_MODEL + m] = (a0 + a1) + (a2 + a3);
  __threadfence();          // release our part writes
  __syncthreads();
  if (m == 0) lastFlag = (atomicAdd(&cnt[b], 1) == JSPLIT - 1);
  __syncthreads();
  if (!lastFlag) return;
  __threadfence();          // acquire: all other blocks' parts now visible
  float p = 0.0f;
#pragma unroll 4
  for (int s2 = 0; s2 < JSPLIT; ++s2)
    p += part[(b * JSPLIT + s2) * D_MODEL + m];
  p *= (1.0f / SEQ_L);
  red0[m] = p * W_cls[m];
  red1[m] = p * W_cls[D_MODEL + m];
  __syncthreads();
  if (m < 64) {
    float v0 = red0[m] + red0[m + 64];
    float v1 = red1[m] + red1[m + 64];
#pragma unroll
    for (int off = 32; off; off >>= 1) {
      v0 += __shfl_xor(v0, off);
      v1 += __shfl_xor(v1, off);
    }
    if (m == 0) {
      out[b * 2 + 0] = v0 + b_cls[0];
      out[b * 2 + 1] = v1 + b_cls[1];
    }
  }
}

extern "C" void kernel_launch(void* const* d_in, const int* in_sizes, int n_in,
                              void* d_out, int out_size, void* d_ws, size_t ws_size,
                              hipStream_t stream) {
  const int*   x      = (const int*)d_in[0];
  const float* emb    = (const float*)d_in[1];
  const float* ln_w   = (const float*)d_in[2];
  const float* ln_b   = (const float*)d_in[3];
  const float* A_log  = (const float*)d_in[4];
  const float* Dp     = (const float*)d_in[5];
  const float* C_re   = (const float*)d_in[6];
  const float* log_dt = (const float*)d_in[7];
  const float* W_cls  = (const float*)d_in[8];
  const float* b_cls  = (const float*)d_in[9];
  float* out = (float*)d_out;

  char* ws = (char*)d_ws;
  float* e_ln = (float*)(ws);                 // 2000*128*4 = 1,024,000 B
  float* Wv   = (float*)(ws + 1048576);       // 4096*128*4 = 2,097,152 B
  float* part = (float*)(ws + 3145728);       // 32*64*128*4 = 1,048,576 B
  int*   cnt  = (int*)(ws + 4194304);         // 32*4 = 128 B

  fused_prep_kernel<<<LN_BLOCKS + W_BLOCKS, 256, 0, stream>>>(
      emb, ln_w, ln_b, A_log, Dp, C_re, log_dt, e_ln, Wv, cnt);
  reduce_final_kernel<<<dim3(BATCH, JSPLIT), 128, 0, stream>>>(
      x, e_ln, Wv, W_cls, b_cls, part, cnt, out);
}

// Round 5
// 30.941 us; speedup vs baseline: 3.5513x; 3.5513x over previous
//
#include <hip/hip_runtime.h>
#include <math.h>

#define D_MODEL 128
#define D_STATE 64
#define VOCAB 2000
#define SEQ_L 4096
#define BATCH 32
#define JSPLIT 64
#define CHUNK (SEQ_L / JSPLIT)   // 64
#define SEG 32                   // j's per weights BLOCK (16 per half-block)
#define SEGH 16
#define LN_BLOCKS (VOCAB / 4)    // 500
#define W_BLOCKS (SEQ_L / SEG)   // 128
#define LN_EPS 1e-5f

// ============ Kernel 1: fused prep (LN-embed ∥ pooled-conv weights) =========
// blocks [0, 500): layernorm 4 vocab rows each -> e_ln
// blocks [500, 628): Wv[j,m] = D_m + sum_n r_mn * (1 - q_mn^{L-j}),
//   q = exp(dt_m*A_n), r = C_mn/(1-q), geometric recurrence over SEGH j's.
// No inter-block communication -> plain fusion, no fences.
__global__ __launch_bounds__(256) void prep_kernel(
    const float* __restrict__ emb, const float* __restrict__ ln_w,
    const float* __restrict__ ln_b, const float* __restrict__ A_log,
    const float* __restrict__ Dp, const float* __restrict__ C_re,
    const float* __restrict__ log_dt, float* __restrict__ e_ln,
    float* __restrict__ Wv) {
  if (blockIdx.x < LN_BLOCKS) {
    int v = blockIdx.x * 4 + (threadIdx.x >> 6);
    int t = threadIdx.x & 63;
    const float* row = emb + v * D_MODEL;
    float h0 = row[t];
    float h1 = row[t + 64];
    float s = h0 + h1;
#pragma unroll
    for (int off = 32; off; off >>= 1) s += __shfl_xor(s, off);
    float mu = s * (1.0f / D_MODEL);
    float d0 = h0 - mu, d1 = h1 - mu;
    float q = d0 * d0 + d1 * d1;
#pragma unroll
    for (int off = 32; off; off >>= 1) q += __shfl_xor(q, off);
    float var = q * (1.0f / D_MODEL);
    float rs = rsqrtf(var + LN_EPS);
    e_ln[v * D_MODEL + t]      = d0 * rs * ln_w[t]      + ln_b[t];
    e_ln[v * D_MODEL + t + 64] = d1 * rs * ln_w[t + 64] + ln_b[t + 64];
  } else {
    __shared__ float Ash[D_STATE];
    if (threadIdx.x < D_STATE) Ash[threadIdx.x] = -expf(A_log[threadIdx.x]);
    __syncthreads();
    int wb = blockIdx.x - LN_BLOCKS;
    int m = threadIdx.x & (D_MODEL - 1);
    int sub = threadIdx.x >> 7;               // 0 or 1
    int j0 = wb * SEG + sub * SEGH;
    float acc[SEGH];
#pragma unroll
    for (int k = 0; k < SEGH; ++k) acc[k] = 0.0f;
    float dt = expf(log_dt[m]);
    float bs = 0.0f;
    float r1_end = (float)(SEQ_L - j0 - (SEGH - 1));
    for (int n = 0; n < D_STATE; ++n) {
      float x = dt * Ash[n];                  // negative
      float q = expf(x);
      float r = C_re[m * D_STATE + n] / (1.0f - q);
      bs += r;
      float g = expf(x * r1_end);             // q^{L - j0 - 15}
      acc[SEGH - 1] += r * g;
#pragma unroll
      for (int jj = SEGH - 2; jj >= 0; --jj) {
        g *= q;
        acc[jj] += r * g;
      }
    }
    float base = Dp[m] + bs;
#pragma unroll
    for (int k = 0; k < SEGH; ++k)
      Wv[(j0 + k) * D_MODEL + m] = base - acc[k];
  }
}

// ============ Kernel 2: gather-weighted reduction ===========================
// part[b,s,m] = sum_{j in chunk s} e_ln[x[b,j], m] * Wv[j, m]
__global__ __launch_bounds__(128) void reduce_kernel(
    const int* __restrict__ x, const float* __restrict__ e_ln,
    const float* __restrict__ Wv, float* __restrict__ part) {
  __shared__ int toks[CHUNK];
  int b = blockIdx.x;
  int sIdx = blockIdx.y;
  int m = threadIdx.x;
  if (m < CHUNK) toks[m] = x[b * SEQ_L + sIdx * CHUNK + m];
  __syncthreads();
  const float* wbase = Wv + sIdx * CHUNK * D_MODEL + m;
  float a0 = 0.0f, a1 = 0.0f, a2 = 0.0f, a3 = 0.0f;
#pragma unroll
  for (int j = 0; j < CHUNK; j += 4) {
    int t0 = toks[j], t1 = toks[j + 1], t2 = toks[j + 2], t3 = toks[j + 3];
    float e0 = e_ln[t0 * D_MODEL + m];
    float e1 = e_ln[t1 * D_MODEL + m];
    float e2 = e_ln[t2 * D_MODEL + m];
    float e3 = e_ln[t3 * D_MODEL + m];
    float w0 = wbase[(j + 0) * D_MODEL];
    float w1 = wbase[(j + 1) * D_MODEL];
    float w2 = wbase[(j + 2) * D_MODEL];
    float w3 = wbase[(j + 3) * D_MODEL];
    a0 = fmaf(e0, w0, a0);
    a1 = fmaf(e1, w1, a1);
    a2 = fmaf(e2, w2, a2);
    a3 = fmaf(e3, w3, a3);
  }
  part[(b * JSPLIT + sIdx) * D_MODEL + m] = (a0 + a1) + (a2 + a3);
}

// ============ Kernel 3: finalize: pool + classifier =========================
__global__ __launch_bounds__(64) void final_kernel(
    const float* __restrict__ part, const float* __restrict__ W_cls,
    const float* __restrict__ b_cls, float* __restrict__ out) {
  int b = blockIdx.x;
  int t = threadIdx.x;  // 0..63
  float p1 = 0.0f, p2 = 0.0f;
#pragma unroll 4
  for (int s = 0; s < JSPLIT; ++s) {
    p1 += part[(b * JSPLIT + s) * D_MODEL + t];
    p2 += part[(b * JSPLIT + s) * D_MODEL + t + 64];
  }
  p1 *= (1.0f / SEQ_L);
  p2 *= (1.0f / SEQ_L);
  float c0 = p1 * W_cls[t]           + p2 * W_cls[t + 64];
  float c1 = p1 * W_cls[D_MODEL + t] + p2 * W_cls[D_MODEL + t + 64];
#pragma unroll
  for (int off = 32; off; off >>= 1) {
    c0 += __shfl_xor(c0, off);
    c1 += __shfl_xor(c1, off);
  }
  if (t == 0) {
    out[b * 2 + 0] = c0 + b_cls[0];
    out[b * 2 + 1] = c1 + b_cls[1];
  }
}

extern "C" void kernel_launch(void* const* d_in, const int* in_sizes, int n_in,
                              void* d_out, int out_size, void* d_ws, size_t ws_size,
                              hipStream_t stream) {
  const int*   x      = (const int*)d_in[0];
  const float* emb    = (const float*)d_in[1];
  const float* ln_w   = (const float*)d_in[2];
  const float* ln_b   = (const float*)d_in[3];
  const float* A_log  = (const float*)d_in[4];
  const float* Dp     = (const float*)d_in[5];
  const float* C_re   = (const float*)d_in[6];
  const float* log_dt = (const float*)d_in[7];
  const float* W_cls  = (const float*)d_in[8];
  const float* b_cls  = (const float*)d_in[9];
  float* out = (float*)d_out;

  char* ws = (char*)d_ws;
  float* e_ln = (float*)(ws);                 // 2000*128*4 = 1,024,000 B
  float* Wv   = (float*)(ws + 1048576);       // 4096*128*4 = 2,097,152 B
  float* part = (float*)(ws + 3145728);       // 32*64*128*4 = 1,048,576 B

  prep_kernel<<<LN_BLOCKS + W_BLOCKS, 256, 0, stream>>>(
      emb, ln_w, ln_b, A_log, Dp, C_re, log_dt, e_ln, Wv);
  reduce_kernel<<<dim3(BATCH, JSPLIT), 128, 0, stream>>>(x, e_ln, Wv, part);
  final_kernel<<<BATCH, 64, 0, stream>>>(part, W_cls, b_cls, out);
}